// Round 1
// baseline (143.372 us; speedup 1.0000x reference)
//
#include <hip/hip_runtime.h>

// SpatialDeformableTransformer:
//   V = bicubic_resize(flow [8,64,64,2] -> [8,512,512,2])   (jax.image.resize "cubic")
//   x_s = V[...,0] + linspace(-1,1,512)[ox];  y_s = V[...,1] + linspace(-1,1,512)[oy]
//   out = bilinear_sample(U, x_s, y_s) with reference's exact conventions.

#define N_B    8
#define IN_HW  512
#define N_C    16
#define F_HW   64
#define OUTHW  512

// Keys cubic kernel, a = -0.5, exactly as jax.image._fill_keys_cubic_kernel
__device__ __forceinline__ float keys_w(float x) {
    // x >= 0
    if (x >= 2.0f) return 0.0f;
    if (x >= 1.0f) return ((-0.5f * x + 2.5f) * x - 4.0f) * x + 2.0f;
    return ((1.5f * x - 2.5f) * x) * x + 1.0f;
}

// jax compute_weight_mat semantics for 64 -> 512, scale = 8, translation = 0:
//   sample_f = (i + 0.5)/8 - 0.5
//   4 candidate taps j = floor(sf)-1 .. floor(sf)+2; taps outside [0,63] excluded;
//   weights renormalized by sum of the included taps.
__device__ __forceinline__ int cubic_taps(int i, float w[4]) {
    float sf = (i + 0.5f) * 0.125f - 0.5f;
    int jf = (int)floorf(sf);
    float sum = 0.0f;
#pragma unroll
    for (int t = 0; t < 4; ++t) {
        int j = jf - 1 + t;
        float wt = 0.0f;
        if (j >= 0 && j < F_HW) wt = keys_w(fabsf(sf - (float)j));
        w[t] = wt;
        sum += wt;
    }
    float inv = 1.0f / sum;
#pragma unroll
    for (int t = 0; t < 4; ++t) w[t] *= inv;
    return jf - 1;
}

__global__ __launch_bounds__(256) void sdt_kernel(const float* __restrict__ U,
                                                  const float* __restrict__ flow,
                                                  float* __restrict__ out) {
    int idx = blockIdx.x * 256 + threadIdx.x;   // output pixel index
    int ox = idx & (OUTHW - 1);
    int oy = (idx >> 9) & (OUTHW - 1);
    int b  = idx >> 18;

    // ---- bicubic upsample of flow at (oy, ox) ----
    float wx[4], wy[4];
    int jx0 = cubic_taps(ox, wx);
    int jy0 = cubic_taps(oy, wy);

    float vx = 0.0f, vy = 0.0f;
    const float* fb = flow + (size_t)b * (F_HW * F_HW * 2);
#pragma unroll
    for (int ty = 0; ty < 4; ++ty) {
        int jy = min(max(jy0 + ty, 0), F_HW - 1);
        float wyt = wy[ty];
        const float* frow = fb + jy * (F_HW * 2);
#pragma unroll
        for (int tx = 0; tx < 4; ++tx) {
            int jx = min(max(jx0 + tx, 0), F_HW - 1);
            float w = wyt * wx[tx];
            float2 f2 = *(const float2*)(frow + jx * 2);
            vx = fmaf(w, f2.x, vx);
            vy = fmaf(w, f2.y, vy);
        }
    }

    // ---- identity grid (linspace(-1,1,512)) ----
    float xg = -1.0f + (2.0f / 511.0f) * (float)ox;
    float yg = -1.0f + (2.0f / 511.0f) * (float)oy;
    float xs = vx + xg;
    float ys = vy + yg;

    // ---- bilinear grid sample, reference conventions ----
    float x = (xs + 1.0f) * (IN_HW / 2.0f);   // (x+1)*W/2, NOT (W-1)/2
    float y = (ys + 1.0f) * (IN_HW / 2.0f);
    float fx0 = floorf(x);
    float fy0 = floorf(y);
    int x0 = min(max((int)fx0, 0), IN_HW - 1);
    int x1 = min(max((int)fx0 + 1, 0), IN_HW - 1);
    int y0 = min(max((int)fy0, 0), IN_HW - 1);
    int y1 = min(max((int)fy0 + 1, 0), IN_HW - 1);
    // weights from CLIPPED corner coordinates (replicates reference exactly)
    float x0f = (float)x0, x1f = (float)x1, y0f = (float)y0, y1f = (float)y1;
    float wa = (x1f - x) * (y1f - y);
    float wb = (x1f - x) * (y - y0f);
    float wc = (x - x0f) * (y1f - y);
    float wd = (x - x0f) * (y - y0f);

    const float4* Ia = (const float4*)(U + (((size_t)b * IN_HW + y0) * IN_HW + x0) * N_C);
    const float4* Ib = (const float4*)(U + (((size_t)b * IN_HW + y1) * IN_HW + x0) * N_C);
    const float4* Ic = (const float4*)(U + (((size_t)b * IN_HW + y0) * IN_HW + x1) * N_C);
    const float4* Id = (const float4*)(U + (((size_t)b * IN_HW + y1) * IN_HW + x1) * N_C);
    float4* O = (float4*)(out + (size_t)idx * N_C);
#pragma unroll
    for (int g = 0; g < 4; ++g) {
        float4 a = Ia[g], bb = Ib[g], c = Ic[g], d = Id[g];
        float4 r;
        r.x = wa * a.x + wb * bb.x + wc * c.x + wd * d.x;
        r.y = wa * a.y + wb * bb.y + wc * c.y + wd * d.y;
        r.z = wa * a.z + wb * bb.z + wc * c.z + wd * d.z;
        r.w = wa * a.w + wb * bb.w + wc * c.w + wd * d.w;
        O[g] = r;
    }
}

extern "C" void kernel_launch(void* const* d_in, const int* in_sizes, int n_in,
                              void* d_out, int out_size, void* d_ws, size_t ws_size,
                              hipStream_t stream) {
    const float* U    = (const float*)d_in[0];
    const float* flow = (const float*)d_in[1];
    float* out        = (float*)d_out;
    const int total_pixels = N_B * OUTHW * OUTHW;      // 2,097,152
    sdt_kernel<<<dim3(total_pixels / 256), dim3(256), 0, stream>>>(U, flow, out);
}

// Round 2
// 77.466 us; speedup vs baseline: 1.8508x; 1.8508x over previous
//
#include <hip/hip_runtime.h>

// SpatialDeformableTransformer, fused:
//   V = bicubic_resize(flow [8,64,64,2] -> [8,512,512,2])   (jax.image.resize "cubic")
//   x_s = V[...,0] + linspace(-1,1,512)[ox];  y_s = V[...,1] + linspace(-1,1,512)[oy]
//   out = bilinear_sample(U, x_s, y_s) with reference's exact conventions.
//
// Layout: 4 threads per output pixel (one float4 channel-group each) so gather
// loads are wave-coalesced; bicubic done once per pixel by wave 0 into LDS.

#define N_B    8
#define IN_HW  512
#define N_C    16
#define F_HW   64
#define OUTHW  512
#define TILE_X 16
#define TILE_Y 4
#define PIX_PER_BLK (TILE_X * TILE_Y)   // 64

// Keys cubic kernel, a = -0.5, exactly as jax.image._fill_keys_cubic_kernel
__device__ __forceinline__ float keys_w(float x) {
    if (x >= 2.0f) return 0.0f;
    if (x >= 1.0f) return ((-0.5f * x + 2.5f) * x - 4.0f) * x + 2.0f;
    return ((1.5f * x - 2.5f) * x) * x + 1.0f;
}

// jax compute_weight_mat semantics for 64 -> 512, scale = 8, translation = 0:
//   sample_f = (i + 0.5)/8 - 0.5; taps j = floor(sf)-1 .. +2; out-of-range taps
//   dropped; weights renormalized by the sum of included taps.
__device__ __forceinline__ int cubic_taps(int i, float w[4]) {
    float sf = (i + 0.5f) * 0.125f - 0.5f;
    int jf = (int)floorf(sf);
    float sum = 0.0f;
#pragma unroll
    for (int t = 0; t < 4; ++t) {
        int j = jf - 1 + t;
        float wt = 0.0f;
        if (j >= 0 && j < F_HW) wt = keys_w(fabsf(sf - (float)j));
        w[t] = wt;
        sum += wt;
    }
    float inv = 1.0f / sum;
#pragma unroll
    for (int t = 0; t < 4; ++t) w[t] *= inv;
    return jf - 1;
}

__global__ __launch_bounds__(256) void sdt_kernel(const float* __restrict__ U,
                                                  const float* __restrict__ flow,
                                                  float* __restrict__ out) {
    __shared__ float2 coords[PIX_PER_BLK];   // (x, y) in input-pixel units

    const int tid = threadIdx.x;
    const int bid = blockIdx.x;
    const int tiles_x = OUTHW / TILE_X;      // 32
    const int tiles_y = OUTHW / TILE_Y;      // 128
    const int tx = bid & (tiles_x - 1);
    const int ty = (bid >> 5) & (tiles_y - 1);
    const int b  = bid >> 12;                // 32*128 = 4096 tiles per batch

    // ---- phase 1: wave 0 computes sampling coords for the block's 64 pixels ----
    if (tid < PIX_PER_BLK) {
        const int p  = tid;
        const int ox = tx * TILE_X + (p & (TILE_X - 1));
        const int oy = ty * TILE_Y + (p >> 4);

        float wx[4], wy[4];
        const int jx0 = cubic_taps(ox, wx);
        const int jy0 = cubic_taps(oy, wy);

        float vx = 0.0f, vy = 0.0f;
        const float* fb = flow + (size_t)b * (F_HW * F_HW * 2);
#pragma unroll
        for (int t = 0; t < 4; ++t) {
            const int jy = min(max(jy0 + t, 0), F_HW - 1);
            const float wyt = wy[t];
            const float* frow = fb + jy * (F_HW * 2);
#pragma unroll
            for (int s = 0; s < 4; ++s) {
                const int jx = min(max(jx0 + s, 0), F_HW - 1);
                const float w = wyt * wx[s];
                const float2 f2 = *(const float2*)(frow + jx * 2);
                vx = fmaf(w, f2.x, vx);
                vy = fmaf(w, f2.y, vy);
            }
        }
        const float xg = -1.0f + (2.0f / 511.0f) * (float)ox;
        const float yg = -1.0f + (2.0f / 511.0f) * (float)oy;
        // reference: x = (xs + 1) * W/2  (NOT (W-1)/2)
        const float x = (vx + xg + 1.0f) * (IN_HW / 2.0f);
        const float y = (vy + yg + 1.0f) * (IN_HW / 2.0f);
        coords[p] = make_float2(x, y);
    }
    __syncthreads();

    // ---- phase 2: all 256 threads gather; 4 threads per pixel ----
    const int p   = tid >> 2;          // pixel within block
    const int chg = tid & 3;           // channel group (float4)
    const float2 c = coords[p];
    const float x = c.x, y = c.y;

    const float fx0 = floorf(x);
    const float fy0 = floorf(y);
    const int x0 = min(max((int)fx0, 0), IN_HW - 1);
    const int x1 = min(max((int)fx0 + 1, 0), IN_HW - 1);
    const int y0 = min(max((int)fy0, 0), IN_HW - 1);
    const int y1 = min(max((int)fy0 + 1, 0), IN_HW - 1);
    // weights from CLIPPED corner coords (replicates reference exactly)
    const float x0f = (float)x0, x1f = (float)x1, y0f = (float)y0, y1f = (float)y1;
    const float wa = (x1f - x) * (y1f - y);
    const float wb = (x1f - x) * (y - y0f);
    const float wc = (x - x0f) * (y1f - y);
    const float wd = (x - x0f) * (y - y0f);

    const float4* Ia = (const float4*)(U + (((size_t)b * IN_HW + y0) * IN_HW + x0) * N_C) + chg;
    const float4* Ib = (const float4*)(U + (((size_t)b * IN_HW + y1) * IN_HW + x0) * N_C) + chg;
    const float4* Ic = (const float4*)(U + (((size_t)b * IN_HW + y0) * IN_HW + x1) * N_C) + chg;
    const float4* Id = (const float4*)(U + (((size_t)b * IN_HW + y1) * IN_HW + x1) * N_C) + chg;

    const float4 a  = *Ia;
    const float4 bb = *Ib;
    const float4 cc = *Ic;
    const float4 dd = *Id;
    float4 r;
    r.x = wa * a.x + wb * bb.x + wc * cc.x + wd * dd.x;
    r.y = wa * a.y + wb * bb.y + wc * cc.y + wd * dd.y;
    r.z = wa * a.z + wb * bb.z + wc * cc.z + wd * dd.z;
    r.w = wa * a.w + wb * bb.w + wc * cc.w + wd * dd.w;

    const int ox = tx * TILE_X + (p & (TILE_X - 1));
    const int oy = ty * TILE_Y + (p >> 4);
    float4* O = (float4*)(out + (((size_t)b * OUTHW + oy) * OUTHW + ox) * N_C) + chg;
    *O = r;
}

extern "C" void kernel_launch(void* const* d_in, const int* in_sizes, int n_in,
                              void* d_out, int out_size, void* d_ws, size_t ws_size,
                              hipStream_t stream) {
    const float* U    = (const float*)d_in[0];
    const float* flow = (const float*)d_in[1];
    float* out        = (float*)d_out;
    const int n_blocks = N_B * (OUTHW / TILE_X) * (OUTHW / TILE_Y);  // 32768
    sdt_kernel<<<dim3(n_blocks), dim3(256), 0, stream>>>(U, flow, out);
}